// Round 1
// baseline (149.700 us; speedup 1.0000x reference)
//
#include <hip/hip_runtime.h>
#include <hip/hip_bf16.h>

#define B 64
#define F 2048
#define BN 64
#define BK 32
#define KSPLIT 4
#define KCHUNK (F / KSPLIT)   // 512
#define NITER (KCHUNK / BK)   // 16
#define LDSW 40               // LDS row stride in shorts (80 B, 16B-aligned rows, ~2-way banks)

typedef __attribute__((ext_vector_type(8))) short bf16x8;
typedef __attribute__((ext_vector_type(4))) float f32x4;

__device__ __forceinline__ unsigned short f2bf(float f) {
  union { float f; unsigned u; } a; a.f = f;
  unsigned r = a.u + 0x7FFFu + ((a.u >> 16) & 1u);
  return (unsigned short)(r >> 16);
}
__device__ __forceinline__ float bf2f(unsigned short h) {
  union { unsigned u; float f; } a; a.u = ((unsigned)h) << 16;
  return a.f;
}

// C[b,f] = sum_k x[b,k] * W[f,k]  via bf16 hi/lo split (3 MFMAs ~ fp32 accuracy).
// Split-K: each block writes its partial to part[(kb*3+mat)*B*F + ...].
__global__ __launch_bounds__(256) void qkv_gemm_kernel(
    const float* __restrict__ x, const float* __restrict__ Wq,
    const float* __restrict__ Wk, const float* __restrict__ Wv,
    float* __restrict__ part) {
  __shared__ __align__(16) short xs_hi[B][LDSW];
  __shared__ __align__(16) short xs_lo[B][LDSW];
  __shared__ __align__(16) short ws_hi[BN][LDSW];
  __shared__ __align__(16) short ws_lo[BN][LDSW];

  const int tid  = threadIdx.x;
  const int f0   = blockIdx.x * BN;
  const int kb   = blockIdx.y;
  const int mat  = blockIdx.z;
  const float* W = (mat == 0) ? Wq : (mat == 1) ? Wk : Wv;

  const int lrow = tid >> 2;           // 0..63 staging row
  const int lc0  = (tid & 3) << 3;     // 0,8,16,24 staging col

  const int wave = tid >> 6;
  const int lane = tid & 63;
  const int l15  = lane & 15;
  const int quad = lane >> 4;

  const float* xg = x + lrow * F + kb * KCHUNK + lc0;
  const float* wg = W + (f0 + lrow) * F + kb * KCHUNK + lc0;

  f32x4 acc[4];
#pragma unroll
  for (int i = 0; i < 4; ++i) acc[i] = (f32x4){0.f, 0.f, 0.f, 0.f};

  float4 xa = *(const float4*)(xg);
  float4 xb = *(const float4*)(xg + 4);
  float4 wa = *(const float4*)(wg);
  float4 wb = *(const float4*)(wg + 4);

  for (int it = 0; it < NITER; ++it) {
    __syncthreads();  // previous iter's LDS reads done
    float xv[8] = {xa.x, xa.y, xa.z, xa.w, xb.x, xb.y, xb.z, xb.w};
    float wv[8] = {wa.x, wa.y, wa.z, wa.w, wb.x, wb.y, wb.z, wb.w};
    bf16x8 xh, xl, wh, wl;
#pragma unroll
    for (int i = 0; i < 8; ++i) {
      unsigned short h = f2bf(xv[i]);
      xh[i] = (short)h;
      xl[i] = (short)f2bf(xv[i] - bf2f(h));
      unsigned short hw = f2bf(wv[i]);
      wh[i] = (short)hw;
      wl[i] = (short)f2bf(wv[i] - bf2f(hw));
    }
    *(bf16x8*)&xs_hi[lrow][lc0] = xh;
    *(bf16x8*)&xs_lo[lrow][lc0] = xl;
    *(bf16x8*)&ws_hi[lrow][lc0] = wh;
    *(bf16x8*)&ws_lo[lrow][lc0] = wl;
    __syncthreads();

    if (it + 1 < NITER) {  // prefetch next chunk under MFMA
      const float* xp = xg + (it + 1) * BK;
      const float* wp = wg + (it + 1) * BK;
      xa = *(const float4*)(xp);
      xb = *(const float4*)(xp + 4);
      wa = *(const float4*)(wp);
      wb = *(const float4*)(wp + 4);
    }

    bf16x8 a_hi = *(const bf16x8*)&xs_hi[(wave << 4) + l15][quad << 3];
    bf16x8 a_lo = *(const bf16x8*)&xs_lo[(wave << 4) + l15][quad << 3];
#pragma unroll
    for (int nt = 0; nt < 4; ++nt) {
      bf16x8 b_hi = *(const bf16x8*)&ws_hi[(nt << 4) + l15][quad << 3];
      bf16x8 b_lo = *(const bf16x8*)&ws_lo[(nt << 4) + l15][quad << 3];
      acc[nt] = __builtin_amdgcn_mfma_f32_16x16x32_bf16(a_hi, b_hi, acc[nt], 0, 0, 0);
      acc[nt] = __builtin_amdgcn_mfma_f32_16x16x32_bf16(a_hi, b_lo, acc[nt], 0, 0, 0);
      acc[nt] = __builtin_amdgcn_mfma_f32_16x16x32_bf16(a_lo, b_hi, acc[nt], 0, 0, 0);
    }
  }

  // epilogue: C/D layout col=lane&15, row=quad*4+reg (m89-verified)
  float* outp = part + (size_t)(kb * 3 + mat) * B * F;
#pragma unroll
  for (int nt = 0; nt < 4; ++nt) {
    int f = f0 + (nt << 4) + l15;
#pragma unroll
    for (int r = 0; r < 4; ++r) {
      int brow = (wave << 4) + (quad << 2) + r;
      outp[brow * F + f] = acc[nt][r];
    }
  }
}

// attended[b,f] = sum_{g unmasked} exp(q_bf*k_g - m) v_g / sum exp(...),
// m = q_bf>=0 ? q_bf*kmax : q_bf*kmin. Masked g contribute exactly 0.
__global__ __launch_bounds__(256) void attn_kernel(
    const float* __restrict__ part, const int* __restrict__ mask,
    float* __restrict__ out) {
  __shared__ __align__(16) float kv[2 * F];
  __shared__ int cnt;
  __shared__ float rmax[4], rmin[4];

  const int b    = blockIdx.x;
  const int tid  = threadIdx.x;
  const int wave = tid >> 6;
  const int lane = tid & 63;

  if (tid == 0) cnt = 0;
  __syncthreads();

  const int f = blockIdx.y * 256 + tid;
  float s = 0.f;
#pragma unroll
  for (int p = 0; p < KSPLIT; ++p) s += part[((p * 3 + 0) * B + b) * F + f];

  // phase 1: compact unmasked (k,v) pairs into LDS (order-free), track kmin/kmax
  float kmax = -3.4e38f, kmin = 3.4e38f;
  for (int c = wave; c < F / 64; c += 4) {
    int g = (c << 6) + lane;
    float kg = 0.f, vg = 0.f;
#pragma unroll
    for (int p = 0; p < KSPLIT; ++p) {
      kg += part[((p * 3 + 1) * B + b) * F + g];
      vg += part[((p * 3 + 2) * B + b) * F + g];
    }
    bool act = (mask[b * F + g] != 0);
    unsigned long long bal = __ballot(act);
    int nw = __popcll(bal);
    int base = 0;
    if (lane == 0) base = atomicAdd(&cnt, nw);
    base = __shfl(base, 0);
    if (act) {
      int pos = base + __popcll(bal & ((1ull << lane) - 1ull));
      kv[2 * pos]     = kg;
      kv[2 * pos + 1] = vg;
      kmax = fmaxf(kmax, kg);
      kmin = fminf(kmin, kg);
    }
  }
#pragma unroll
  for (int o = 32; o > 0; o >>= 1) {
    kmax = fmaxf(kmax, __shfl_xor(kmax, o));
    kmin = fminf(kmin, __shfl_xor(kmin, o));
  }
  if (lane == 0) { rmax[wave] = kmax; rmin[wave] = kmin; }
  __syncthreads();
  kmax = fmaxf(fmaxf(rmax[0], rmax[1]), fmaxf(rmax[2], rmax[3]));
  kmin = fminf(fminf(rmin[0], rmin[1]), fminf(rmin[2], rmin[3]));
  const int n = cnt;

  if (n == 0) {  // all-masked row: reference softmax is uniform -> mean(v)
    float sum = 0.f;
    for (int g = 0; g < F; ++g) {
      float vg = 0.f;
      for (int p = 0; p < KSPLIT; ++p) vg += part[((p * 3 + 2) * B + b) * F + g];
      sum += vg;
    }
    out[b * F + f] = sum / (float)F;
    return;
  }

  const float L2E = 1.44269504088896f;
  float se = s * L2E;
  float m2 = se * ((s >= 0.f) ? kmax : kmin);
  float num0 = 0.f, num1 = 0.f, den0 = 0.f, den1 = 0.f;
  int n2 = n & ~1;
  for (int j = 0; j < n2; j += 2) {
    float4 p = *(const float4*)&kv[2 * j];  // (k0,v0,k1,v1) broadcast
    float e0 = exp2f(fmaf(se, p.x, -m2));
    float e1 = exp2f(fmaf(se, p.z, -m2));
    num0 = fmaf(e0, p.y, num0); den0 += e0;
    num1 = fmaf(e1, p.w, num1); den1 += e1;
  }
  if (n & 1) {
    float e = exp2f(fmaf(se, kv[2 * n2], -m2));
    num0 = fmaf(e, kv[2 * n2 + 1], num0); den0 += e;
  }
  out[b * F + f] = (num0 + num1) / (den0 + den1);
}

extern "C" void kernel_launch(void* const* d_in, const int* in_sizes, int n_in,
                              void* d_out, int out_size, void* d_ws, size_t ws_size,
                              hipStream_t stream) {
  const float* x  = (const float*)d_in[0];
  const int* mask = (const int*)d_in[1];
  const float* Wq = (const float*)d_in[2];
  const float* Wk = (const float*)d_in[3];
  const float* Wv = (const float*)d_in[4];
  float* out  = (float*)d_out;
  float* part = (float*)d_ws;  // KSPLIT*3*B*F floats = 6 MB, fully overwritten

  dim3 gg(F / BN, KSPLIT, 3);
  qkv_gemm_kernel<<<gg, 256, 0, stream>>>(x, Wq, Wk, Wv, part);
  dim3 ga(B, F / 256);
  attn_kernel<<<ga, 256, 0, stream>>>(part, mask, out);
}